// Round 6
// baseline (956.321 us; speedup 1.0000x reference)
//
#include <hip/hip_runtime.h>

#define DEVINL static __device__ __forceinline__
// Same-wave LDS ordering: compiler reorder fence only (validated r10/r12).
#define CFENCE() asm volatile("" ::: "memory")

typedef float v2f __attribute__((ext_vector_type(2)));

DEVINL v2f mk2(float a, float b) { v2f r; r.x = a; r.y = b; return r; }
DEVINL v2f pkfma(v2f a, v2f b, v2f c) { return __builtin_elementwise_fma(a, b, c); }

constexpr float KE = 2.885390081777927f;   // 2*log2(e)

#if __has_builtin(__builtin_amdgcn_exp2f)
DEVINL float exp2_fast(float x) { return __builtin_amdgcn_exp2f(x); }
#else
DEVINL float exp2_fast(float x) { return __expf(x * 0.6931471805599453f); }
#endif

// tanh(x) with t = x*2*log2(e) pre-folded into weights: 1 - 2/(2^t+1).
DEVINL float tanh_pre(float t) {
  float e = exp2_fast(t);
  return 1.0f - 2.0f * __builtin_amdgcn_rcpf(e + 1.0f);
}

template <int CTRL>
DEVINL float dpp_add(float v) {
  int t = __builtin_amdgcn_update_dpp(0, __float_as_int(v), CTRL, 0xF, 0xF, true);
  return v + __int_as_float(t);
}
DEVINL float rlane(float v, int l) {
  return __int_as_float(__builtin_amdgcn_readlane(__float_as_int(v), l));
}
// 4-stage row-local DPP partial sums: every lane of each 16-lane row holds
// that row's 16-sum. 32-sums via readlane pairs (commutative pair-add ->
// bit-identical to the validated row_bcast15 variant).
DEVINL float psum4(float v) {
  v = dpp_add<0xB1>(v);    // quad_perm [1,0,3,2]
  v = dpp_add<0x4E>(v);    // quad_perm [2,3,0,1]
  v = dpp_add<0x141>(v);   // row_half_mirror
  v = dpp_add<0x140>(v);   // row_mirror -> 16-sums per row
  return v;
}

// 32-wide dot vs an LDS row (uniform address per half), packed fp32.
DEVINL float dot32(const float* hrow, const v2f* W, float bias) {
  const float4* hp = (const float4*)hrow;
  v2f a0 = mk2(bias, 0.f), a1 = mk2(0.f, 0.f);
  v2f a2 = mk2(0.f, 0.f), a3 = mk2(0.f, 0.f);
#pragma unroll
  for (int q = 0; q < 8; q += 2) {
    float4 x = hp[q], y = hp[q + 1];
    a0 = pkfma(mk2(x.x, x.y), W[2 * q + 0], a0);
    a1 = pkfma(mk2(x.z, x.w), W[2 * q + 1], a1);
    a2 = pkfma(mk2(y.x, y.y), W[2 * q + 2], a2);
    a3 = pkfma(mk2(y.z, y.w), W[2 * q + 3], a3);
  }
  v2f s = (a0 + a1) + (a2 + a3);
  return s.x + s.y;
}
// 16-wide partial dot (k-split r3 layer 1), packed fp32.
DEVINL float pdot16(const float* hrow, const v2f* W) {
  const float4* hp = (const float4*)hrow;
  v2f a0 = mk2(0.f, 0.f), a1 = mk2(0.f, 0.f);
  float4 x = hp[0], y = hp[1];
  a0 = pkfma(mk2(x.x, x.y), W[0], a0);
  a1 = pkfma(mk2(x.z, x.w), W[1], a1);
  a0 = pkfma(mk2(y.x, y.y), W[2], a0);
  a1 = pkfma(mk2(y.z, y.w), W[3], a1);
  x = hp[2]; y = hp[3];
  a0 = pkfma(mk2(x.x, x.y), W[4], a0);
  a1 = pkfma(mk2(x.z, x.w), W[5], a1);
  a0 = pkfma(mk2(y.x, y.y), W[6], a0);
  a1 = pkfma(mk2(y.z, y.w), W[7], a1);
  v2f s = a0 + a1;
  return s.x + s.y;
}

constexpr int TT = 256;

// wave = 2 batch elements, BOTH using the full-64-lane duty-split layout
// (lanes 0-31 = net r1 / z duties, lanes 32-63 = net r2 / z4 duties).
// The two elements form two INDEPENDENT dependency chains interleaved in
// one instruction stream -> intra-wave latency hiding. Weights are shared.
// grid 2048 -> 2 waves/EU; waves_per_eu(2,2) -> 256-VGPR budget.
__global__ __attribute__((amdgpu_flat_work_group_size(64, 64)))
__attribute__((amdgpu_waves_per_eu(2, 2))) void reac_kernel(
    const float* __restrict__ useq,   // [B][T] f32
    const float* __restrict__ xz0,    // [B][26] f32
    const float* __restrict__ r1W0, const float* __restrict__ r1b0,
    const float* __restrict__ r1W1, const float* __restrict__ r1b1,
    const float* __restrict__ r1W2, const float* __restrict__ r1b2,
    const float* __restrict__ r2W0, const float* __restrict__ r2b0,
    const float* __restrict__ r2W1, const float* __restrict__ r2b1,
    const float* __restrict__ r2W2, const float* __restrict__ r2b2,
    const float* __restrict__ r3W0, const float* __restrict__ r3b0,
    const float* __restrict__ r3W1, const float* __restrict__ r3b1,
    const float* __restrict__ r3W2, const float* __restrict__ r3b2,
    float2* __restrict__ out)         // [B][T] -> (x0,x1) f32
{
  const int lane = threadIdx.x;
  const int j = lane & 31;
  const bool hi = lane >= 32;      // duty selector (r2 net / z4 duties)
  const int b = blockIdx.x;
  const int xaddr = ((lane ^ 32) << 2);   // ds_bpermute partner address

  auto xchg = [&](float v) -> float {
    return __int_as_float(__builtin_amdgcn_ds_bpermute(xaddr, __float_as_int(v)));
  };

  // ---- per-half net weights (column j), tanh prescale KE folded in ----
  const float* W0p = hi ? r2W0 : r1W0;
  const float* B0p = hi ? r2b0 : r1b0;
  const float* W1p = hi ? r2W1 : r1W1;
  const float* B1p = hi ? r2b1 : r1b1;
  const float* W2p = hi ? r2W2 : r1W2;
  const float sc = hi ? 0.2f : 0.3f;
  float w0K = W0p[j] * KE, b0K = B0p[j] * KE;
  float b1K = B1p[j] * KE;
  float w2sc = W2p[j] * sc;

  v2f W1v[16];
#pragma unroll
  for (int k = 0; k < 16; ++k)
    W1v[k] = mk2(W1p[(2 * k) * 32 + j] * KE, W1p[(2 * k + 1) * 32 + j] * KE);

  // r3 layer-0 weights, per-half arrangement over the 12 aligned z-pairs:
  //   low  (A(z)):      pair m -> rows (2m, 2m+1)
  //   high (A(z4) pre): pair 0 unused (0); pairs 1..7 -> rows (2m-2, 2m-1);
  //                     pairs 8..11 (upseq) as low. x-pair rows (14,15)
  //                     deferred to WXv, applied once x is live.
  v2f W0Cv[12];
#pragma unroll
  for (int m = 0; m < 12; ++m) {
    int r = (hi && m >= 1 && m <= 7) ? (2 * m - 2) : (2 * m);
    v2f w = mk2(r3W0[r * 32 + j] * KE, r3W0[(r + 1) * 32 + j] * KE);
    if (hi && m == 0) w = mk2(0.f, 0.f);
    W0Cv[m] = w;
  }
  v2f WXv = mk2(r3W0[14 * 32 + j] * KE, r3W0[15 * 32 + j] * KE);

  const int kbase = hi ? 16 : 0;
  v2f W1Cv[8];
#pragma unroll
  for (int k = 0; k < 8; ++k)
    W1Cv[k] = mk2(r3W1[(kbase + 2 * k) * 32 + j] * KE,
                  r3W1[(kbase + 2 * k + 1) * 32 + j] * KE);
  float b0CK = r3b0[j] * KE, b1CK = r3b1[j] * KE;
  float w2C02 = r3W2[j] * 0.2f;

  // wave-uniform scalars (biases folded with output scales)
  const float b2sA = r1b2[0] * 0.3f;
  const float b2sB = r2b2[0] * 0.2f;
  const float b2Cs = r3b2[0] * 0.2f - 0.05f;   // folds -F/V*0.5 of dCb

  __shared__ __align__(16) float zsS[2][24];      // [elem] z state
  __shared__ __align__(16) float h12S[2][2][32];  // [elem][net][neuron]
  __shared__ __align__(16) float hR3S[2][3][32];  // [elem][z,z23,z4][neuron]

  // Per-element state (A = elem 2b, B = elem 2b+1). All wave-wide.
  struct Elem {
    float x0, x1, Az, rc1, u;
    v2f aa4, ab4;          // carried A(z4)-prefix accumulators (high half)
    float* zs; float* h12; float* hR3;
    const float* up; float2* outp;
  } EA, EB;
  EA.zs = &zsS[0][0]; EA.h12 = &h12S[0][0][0]; EA.hR3 = &hR3S[0][0][0];
  EB.zs = &zsS[1][0]; EB.h12 = &h12S[1][0][0]; EB.hR3 = &hR3S[1][0][0];
  EA.up = useq + (2 * b + 0) * TT; EA.outp = out + (2 * b + 0) * TT;
  EB.up = useq + (2 * b + 1) * TT; EB.outp = out + (2 * b + 1) * TT;

  EA.x0 = xz0[(2 * b + 0) * 26 + 0]; EA.x1 = xz0[(2 * b + 0) * 26 + 1];
  EB.x0 = xz0[(2 * b + 1) * 26 + 0]; EB.x1 = xz0[(2 * b + 1) * 26 + 1];
  if (!hi && j < 24) EA.zs[j] = xz0[(2 * b + 0) * 26 + 2 + j];
  if (hi && j < 24)  EB.zs[j] = xz0[(2 * b + 1) * 26 + 2 + j];
  CFENCE();

  // r3 layer-0 over E.zs: low lanes accumulate A(z), high lanes the
  // A(z4)-prefix (per-half W0Cv mapping). Sets E.aa4/E.ab4/E.Az.
  auto r3_l0 = [&](Elem& E) {
    const float4* zp = (const float4*)E.zs;
    float4 z0 = zp[0], z1 = zp[1], z2 = zp[2], z3 = zp[3];
    float4 u0 = zp[4], u1 = zp[5];
    v2f aa = mk2(b0CK, 0.f), ab = mk2(0.f, 0.f);
    aa = pkfma(mk2(z0.x, z0.y), W0Cv[0], aa);
    ab = pkfma(mk2(z0.z, z0.w), W0Cv[1], ab);
    aa = pkfma(mk2(z1.x, z1.y), W0Cv[2], aa);
    ab = pkfma(mk2(z1.z, z1.w), W0Cv[3], ab);
    aa = pkfma(mk2(z2.x, z2.y), W0Cv[4], aa);
    ab = pkfma(mk2(z2.z, z2.w), W0Cv[5], ab);
    aa = pkfma(mk2(z3.x, z3.y), W0Cv[6], aa);
    ab = pkfma(mk2(z3.z, z3.w), W0Cv[7], ab);
    aa = pkfma(mk2(u0.x, u0.y), W0Cv[8], aa);
    ab = pkfma(mk2(u0.z, u0.w), W0Cv[9], ab);
    aa = pkfma(mk2(u1.x, u1.y), W0Cv[10], aa);
    ab = pkfma(mk2(u1.z, u1.w), W0Cv[11], ab);
    E.aa4 = aa; E.ab4 = ab;
    v2f s = aa + ab;
    E.Az = s.x + s.y;        // meaningful on low lanes (A(z))
  };
  auto rc1_eval = [&](Elem& E) -> float {
    float p0 = pdot16(&E.hR3[kbase], W1Cv);
    float o0 = p0 + xchg(p0) + b1CK;
    float v = psum4(tanh_pre(o0) * w2C02);
    return (rlane(v, 15) + rlane(v, 31)) + b2Cs;
  };
  // RK stage: layer-0 hidden (pre-broadcast) / finish after broadcast.
  auto net_pre = [&](float sxv, float syv) -> float {
    float sv = hi ? syv : sxv;
    return tanh_pre(fmaf(sv, w0K, b0K));
  };
  auto net_post = [&](Elem& E, float sxv, float syv, float rc_m05,
                      float CafF, float& kx, float& ky) {
    float a = dot32(&E.h12[hi ? 32 : 0], W1v, b1K);
    float v = psum4(tanh_pre(a) * w2sc);
    float ra = (rlane(v, 15) + rlane(v, 31)) + b2sA;   // r1 (uniform)
    float rb = (rlane(v, 47) + rlane(v, 63)) + b2sB;   // r2 (uniform)
    float dCa = fmaf(-0.03f, sxv, CafF) - ra;
    float dCb = fmaf(-0.02f, syv, fmaf(-3.0f, rb, ra) + rc_m05);
    kx = dCa * (1.0f / 0.3f);
    ky = dCb * (1.0f / 0.2f);
  };

  // ---- prologue: pipeline state for t=0 (both elements) ----
  r3_l0(EA);
  r3_l0(EB);
  {
    float h0A = tanh_pre(EA.Az);
    float h0B = tanh_pre(EB.Az);
    CFENCE();
    if (!hi) { EA.hR3[j] = h0A; EB.hR3[j] = h0B; }
    CFENCE();
  }
  EA.rc1 = rc1_eval(EA);
  EB.rc1 = rc1_eval(EB);
  EA.u = EA.up[0];
  EB.u = EB.up[0];

  for (int t = 0; t < TT; ++t) {
    int tn = (t < TT - 1) ? (t + 1) : t;
    float uAn = EA.up[tn], uBn = EB.up[tn];   // prefetch
    float CafFA = fmaf(EA.u, 0.05f, 0.05f);
    float CafFB = fmaf(EB.u, 0.05f, 0.05f);

    {
      float2 val = hi ? make_float2(EB.x0, EB.x1) : make_float2(EA.x0, EA.x1);
      float2* addr = hi ? EB.outp : EA.outp;
      if (j == 0) addr[t] = val;     // lanes 0 and 32 store A and B
    }

    // R0: z4 completion + z23 by linearity; stage-1 hiddens. (A ∥ B)
    EA.ab4 = pkfma(mk2(EA.x0, EA.x1), WXv, EA.ab4);
    EB.ab4 = pkfma(mk2(EB.x0, EB.x1), WXv, EB.ab4);
    v2f s4A = EA.aa4 + EA.ab4;
    v2f s4B = EB.aa4 + EB.ab4;
    float A4A = s4A.x + s4A.y;             // A(z4) on high lanes
    float A4B = s4B.x + s4B.y;
    float ApA = xchg(hi ? A4A : EA.Az);
    float ApB = xchg(hi ? A4B : EB.Az);
    float tgA = hi ? A4A : (0.5f * (EA.Az + ApA));   // z23 on low half
    float tgB = hi ? A4B : (0.5f * (EB.Az + ApB));
    float hhA = tanh_pre(tgA);
    float hhB = tanh_pre(tgB);
    float h1A = net_pre(EA.x0, EA.x1);
    float h1B = net_pre(EB.x0, EB.x1);
    CFENCE();
    // R1: LDS broadcasts
    EA.hR3[32 * (1 + (hi ? 1 : 0)) + j] = hhA;  // low->h(z23), high->h(z4)
    EB.hR3[32 * (1 + (hi ? 1 : 0)) + j] = hhB;
    EA.h12[(hi ? 32 : 0) + j] = h1A;
    EB.h12[(hi ? 32 : 0) + j] = h1B;
    CFENCE();
    // R2: head finish (rc23/rc4) + stage-1 finish + stage-2 hiddens (A ∥ B)
    float p1A = pdot16(&EA.hR3[32 + kbase], W1Cv);
    float p2A = pdot16(&EA.hR3[64 + kbase], W1Cv);
    float p1B = pdot16(&EB.hR3[32 + kbase], W1Cv);
    float p2B = pdot16(&EB.hR3[64 + kbase], W1Cv);
    float o1A = p1A + xchg(p1A) + b1CK;
    float o2A = p2A + xchg(p2A) + b1CK;
    float o1B = p1B + xchg(p1B) + b1CK;
    float o2B = p2B + xchg(p2B) + b1CK;
    float vvA = psum4(tanh_pre(hi ? o2A : o1A) * w2C02);
    float vvB = psum4(tanh_pre(hi ? o2B : o1B) * w2C02);
    float rc23A = (rlane(vvA, 15) + rlane(vvA, 31)) + b2Cs;
    float rc4A  = (rlane(vvA, 47) + rlane(vvA, 63)) + b2Cs;
    float rc23B = (rlane(vvB, 15) + rlane(vvB, 31)) + b2Cs;
    float rc4B  = (rlane(vvB, 47) + rlane(vvB, 63)) + b2Cs;
    float kx1A, ky1A, kx1B, ky1B;
    net_post(EA, EA.x0, EA.x1, EA.rc1, CafFA, kx1A, ky1A);
    net_post(EB, EB.x0, EB.x1, EB.rc1, CafFB, kx1B, ky1B);
    float sx2A = fmaf(kx1A, 0.5f, EA.x0), sy2A = fmaf(ky1A, 0.5f, EA.x1);
    float sx2B = fmaf(kx1B, 0.5f, EB.x0), sy2B = fmaf(ky1B, 0.5f, EB.x1);
    float h2A = net_pre(sx2A, sy2A);
    float h2B = net_pre(sx2B, sy2B);
    CFENCE();
    // R3
    EA.h12[(hi ? 32 : 0) + j] = h2A;
    EB.h12[(hi ? 32 : 0) + j] = h2B;
    CFENCE();
    // R4a: stage-2 finish || z-shift reads (A ∥ B)
    float kx2A, ky2A, kx2B, ky2B;
    net_post(EA, sx2A, sy2A, rc23A, CafFA, kx2A, ky2A);
    net_post(EB, sx2B, sy2B, rc23B, CafFB, kx2B, ky2B);
    int src = (j < 14) ? (j + 2) : ((j < 23) ? (j + 1) : 0);
    float zrA = EA.zs[src];
    float zrB = EB.zs[src];
    float znA = (j == 14) ? EA.x0
              : ((j == 15) ? EA.x1 : ((j == 23) ? EA.u : zrA));
    float znB = (j == 14) ? EB.x0
              : ((j == 15) ? EB.x1 : ((j == 23) ? EB.u : zrB));
    CFENCE();                 // zs reads complete before the writes
    if (!hi && j < 24) EA.zs[j] = znA;
    if (hi && j < 24)  EB.zs[j] = znB;
    float sx3A = fmaf(kx2A, 0.5f, EA.x0), sy3A = fmaf(ky2A, 0.5f, EA.x1);
    float sx3B = fmaf(kx2B, 0.5f, EB.x0), sy3B = fmaf(ky2B, 0.5f, EB.x1);
    float h3A = net_pre(sx3A, sy3A);
    float h3B = net_pre(sx3B, sy3B);
    CFENCE();
    // R4b: next-step r3 layer-0 (reads shifted zs) (A ∥ B)
    r3_l0(EA);               // sets EA.aa4/ab4/Az for t+1
    r3_l0(EB);
    float h0nA = tanh_pre(EA.Az);
    float h0nB = tanh_pre(EB.Az);
    if (!hi) { EA.hR3[j] = h0nA; EB.hR3[j] = h0nB; }
    CFENCE();
    // R5
    EA.h12[(hi ? 32 : 0) + j] = h3A;
    EB.h12[(hi ? 32 : 0) + j] = h3B;
    CFENCE();
    // R6: stage-3 finish || rc1 for t+1 || stage-4 hiddens (A ∥ B)
    float kx3A, ky3A, kx3B, ky3B;
    net_post(EA, sx3A, sy3A, rc23A, CafFA, kx3A, ky3A);
    net_post(EB, sx3B, sy3B, rc23B, CafFB, kx3B, ky3B);
    float rc1An = rc1_eval(EA);
    float rc1Bn = rc1_eval(EB);
    float sx4A = EA.x0 + kx3A, sy4A = EA.x1 + ky3A;
    float sx4B = EB.x0 + kx3B, sy4B = EB.x1 + ky3B;
    float h4A = net_pre(sx4A, sy4A);
    float h4B = net_pre(sx4B, sy4B);
    CFENCE();
    // R7
    EA.h12[(hi ? 32 : 0) + j] = h4A;
    EB.h12[(hi ? 32 : 0) + j] = h4B;
    CFENCE();
    // R8: stage-4 finish + state update (A ∥ B)
    float kx4A, ky4A, kx4B, ky4B;
    net_post(EA, sx4A, sy4A, rc4A, CafFA, kx4A, ky4A);
    net_post(EB, sx4B, sy4B, rc4B, CafFB, kx4B, ky4B);
    EA.x0 += (kx1A + 2.0f * (kx2A + kx3A) + kx4A) * (1.0f / 6.0f);
    EA.x1 += (ky1A + 2.0f * (ky2A + ky3A) + ky4A) * (1.0f / 6.0f);
    EB.x0 += (kx1B + 2.0f * (kx2B + kx3B) + kx4B) * (1.0f / 6.0f);
    EB.x1 += (ky1B + 2.0f * (ky2B + ky3B) + ky4B) * (1.0f / 6.0f);
    EA.rc1 = rc1An; EB.rc1 = rc1Bn;
    EA.u = uAn; EB.u = uBn;
    CFENCE();
  }
}

extern "C" void kernel_launch(void* const* d_in, const int* in_sizes, int n_in,
                              void* d_out, int out_size, void* d_ws, size_t ws_size,
                              hipStream_t stream) {
  const float* p[20];
  for (int i = 0; i < 20; ++i) p[i] = (const float*)d_in[i];
  reac_kernel<<<dim3(2048), dim3(64), 0, stream>>>(
      p[0], p[1], p[2], p[3], p[4], p[5], p[6], p[7], p[8], p[9], p[10],
      p[11], p[12], p[13], p[14], p[15], p[16], p[17], p[18], p[19],
      (float2*)d_out);
}